// Round 14
// baseline (91.671 us; speedup 1.0000x reference)
//
#include <hip/hip_runtime.h>

// Partial Radon transform:
//  x: (4, 1, 256, 256) f32 -> out: (4, 5, 256, 180) f32
//
// Round 14 = R13 (correct two-pass, 2 blocks/CU by LDS) with the min-waves
// launch-bounds arg REMOVED. R13's failure was VGPR=24 (compiler minimized
// under the (1024,8) hint -> serialized code, VALU-busy-time 31->47 us).
// R11/R12 show this sample code naturally compiles to 52-64 VGPR, which is
// already <=64 and thus compatible with 2 blocks/CU x 16 waves = 8/SIMD.
// Gate: VGPR must land 48..64; >64 loses the second block and the round
// fails (fallback = R12).

constexpr int WIDTH  = 256;
constexpr int NANG   = 180;
constexpr int NBATCH = 4;
constexpr int NS     = 5;
constexpr int CSTR   = 131;   // dword cells per slow-row; 131%32=3
constexpr int LROWS  = 131;   // local slow-rows per pass
constexpr int SPLIT  = 130;   // padded-slow split boundary

typedef _Float16 h2 __attribute__((ext_vector_type(2)));

#if __has_builtin(__builtin_amdgcn_fractf)
#define FRACT(x) __builtin_amdgcn_fractf(x)
#else
#define FRACT(x) ((x) - floorf(x))
#endif

__device__ inline unsigned pack2_f16(float a, float b) {
    _Float16 ha = (_Float16)a, hb = (_Float16)b;
    unsigned short ua = __builtin_bit_cast(unsigned short, ha);
    unsigned short ub = __builtin_bit_cast(unsigned short, hb);
    return (unsigned)ua | ((unsigned)ub << 16);
}

__global__ __launch_bounds__(1024) void radon_kernel(const float* __restrict__ x,
                                                     float* __restrict__ out) {
    __shared__ unsigned cells[LROWS * CSTR];   // 68,644 B -> 2 blocks/CU

    const int bid = blockIdx.x;
    const int lin = (bid & 7) * 90 + (bid >> 3);   // XCD swizzle, bijective
    const int n = lin / NANG;
    const int a = lin - n * NANG;
    const int t = threadIdx.x;
    const int w = t & 255;
    const int quarter = t >> 8;          // contiguous 64-h range per quarter

    const float* __restrict__ img = x + (size_t)n * WIDTH * WIDTH;

    const float theta = (float)a * 0.017453292519943295f;
    float s, c;
    sincosf(theta, &s, &c);
    const bool transp = (c * c > s * s);

    const float bw  = ((float)w + 0.5f) * (2.0f / WIDTH) - 1.0f;
    const float bh0 = 0.5f * (2.0f / WIDTH) - 1.0f;
    const float gx0 = c * bw + s * bh0;
    const float gy0 = -s * bw + c * bh0;
    const float ix0 = ((gx0 + 1.0f) * (float)WIDTH - 1.0f) * 0.5f;
    const float iy0 = ((gy0 + 1.0f) * (float)WIDTH - 1.0f) * 0.5f;

    const float fast0 = (transp ? iy0 : ix0) + 2.0f;
    const float slow0 = (transp ? ix0 : iy0) + 2.0f;
    const float dfast = transp ? c : s;
    const float dslow = transp ? s : c;

    float r0 = 0.f, r1 = 0.f, r2 = 0.f, r3 = 0.f, r4 = 0.f;

    for (int pass = 0; pass < 2; ++pass) {
        // ---- zero-fill (disjoint from staging) ----
        if (t < LROWS) {                     // cols j=0,129,130 every local row
            const int b = t * CSTR;
            cells[b] = 0u; cells[b + 129] = 0u; cells[b + 130] = 0u;
        }
        if (pass == 0) {
            for (int i = t; i < 2 * CSTR; i += 1024) cells[i] = 0u;              // rows 0,1
        } else {
            for (int i = t; i < 3 * CSTR; i += 1024) cells[128 * CSTR + i] = 0u; // rows 128..130
        }

        // ---- stage this pass's half ----
        // pass 0: orig slow 0..128 -> local 2..130 ; pass 1: orig 128..255 -> local 0..127
        if (!transp) {
            const int nrows = pass ? 128 : 129;
            const int glo   = pass ? 128 : 0;
            for (int d = t; d < nrows * 128; d += 1024) {
                const int ys = d >> 7, xd = d & 127;
                const float2 v = ((const float2*)img)[(glo + ys) * 128 + xd];
                const int loc = pass ? ys : (ys + 2);
                cells[loc * CSTR + xd + 1] = pack2_f16(v.x, v.y);
            }
        } else {
            const bool part = pass ? (w >= 128) : (w <= 128);
            if (part) {
                const int loc = pass ? (w - 128) : (w + 2);
                for (int yp = quarter; yp < 128; yp += 4) {
                    const float v0 = img[(2 * yp) * WIDTH + w];
                    const float v1 = img[(2 * yp + 1) * WIDTH + w];
                    cells[loc * CSTR + yp + 1] = pack2_f16(v0, v1);
                }
            }
        }
        __syncthreads();

        // ---- per-thread h-window (slack 3; predicate m is exact) ----
        const float hstar = (130.0f - slow0) / dslow;
        const float hcl = fminf(fmaxf(hstar, -10000.0f), 10000.0f);
        int lo, hi;
        if (dslow > 0.0f) {
            if (pass == 0) { lo = 0;            hi = (int)hcl + 3; }
            else           { lo = (int)hcl - 3; hi = 256; }
        } else if (dslow < 0.0f) {
            if (pass == 0) { lo = (int)hcl - 3; hi = 256; }
            else           { lo = 0;            hi = (int)hcl + 3; }
        } else { lo = 0; hi = 256; }
        lo = max(lo, 0); hi = min(hi, 256);

        int wlo = lo, whi = hi;
        for (int off = 1; off < 64; off <<= 1) {
            wlo = min(wlo, __shfl_xor(wlo, off));
            whi = max(whi, __shfl_xor(whi, off));
        }
        wlo = __builtin_amdgcn_readfirstlane(wlo);   // scalar loop bounds
        whi = __builtin_amdgcn_readfirstlane(whi);

        auto sample = [&](int h) -> float {
            const float hf = (float)h;
            float fa = fmaf(hf, dfast, fast0);
            float sl = fmaf(hf, dslow, slow0);
            fa = __builtin_amdgcn_fmed3f(fa, 1.0f, 258.0f);
            sl = __builtin_amdgcn_fmed3f(sl, 1.0f, 258.0f);
            const bool m = (sl < 130.0f) == (pass == 0);   // exact partition
            const int fi = (int)fa, si = (int)sl;          // trunc == floor
            const float wf = FRACT(fa);
            const float ws = FRACT(sl);
            const int j = fi >> 1;
            const int sh = (fi & 1) << 4;
            int siL = si - SPLIT * pass;
            siL = min(max(siL, 0), 129);   // m-true reads exact; junk discarded
            const unsigned* rowA = &cells[siL * CSTR + j];
            const unsigned loA = rowA[0],    hiA = rowA[1];
            const unsigned loB = rowA[CSTR], hiB = rowA[CSTR + 1];
            const unsigned pa = __builtin_amdgcn_alignbit(hiA, loA, sh);
            const unsigned pb = __builtin_amdgcn_alignbit(hiB, loB, sh);
            const h2 va = __builtin_bit_cast(h2, pa);
            const h2 vb = __builtin_bit_cast(h2, pb);
            const _Float16 wsh = (_Float16)ws;
            const h2 ws2 = {wsh, wsh};
            const h2 col = (vb - va) * ws2 + va;    // packed lerp, slow axis
            const float c0 = (float)col.x;
            const float c1 = (float)col.y;
            const float val = fmaf(wf, c1 - c0, c0);
            return m ? val : 0.0f;
        };

        // Ring bands, contiguous per quarter (NO phase interleave):
        //  r4:[0,32)u[224,256)  r3:[32,64)u[192,224)
        //  r2:[64,96)u[160,192) r1:[96,127)u[129,160) r0:{127,128}
        #define SEG(LO, HI, R) { \
            const int hs = max(LO, wlo), he = min(HI, whi); \
            _Pragma("unroll 8") \
            for (int h = hs; h < he; ++h) R += sample(h); }
        if (quarter == 0) {
            SEG(0, 32, r4)
            SEG(32, 64, r3)
        } else if (quarter == 1) {
            SEG(64, 96, r2)
            SEG(96, 127, r1)
            if (127 >= wlo && 127 < whi) r0 += sample(127);
        } else if (quarter == 2) {
            if (128 >= wlo && 128 < whi) r0 += sample(128);
            SEG(129, 160, r1)
            SEG(160, 192, r2)
        } else {
            SEG(192, 224, r3)
            SEG(224, 256, r4)
        }
        #undef SEG

        __syncthreads();   // sampling done before next pass overwrites LDS
    }

    // ---- cross-quarter reduction via LDS reuse ----
    float* red = (float*)cells;            // 1024*5 floats = 20,480 B
    const int base = t * NS;
    red[base + 0] = r0;
    red[base + 1] = r1;
    red[base + 2] = r2;
    red[base + 3] = r3;
    red[base + 4] = r4;
    __syncthreads();

    if (t < 256) {
        const int b0 = t * NS, b1 = b0 + 256 * NS, b2 = b0 + 512 * NS, b3 = b0 + 768 * NS;
        const float s0 = (red[b0+0] + red[b1+0]) + (red[b2+0] + red[b3+0]);
        const float s1 = (red[b0+1] + red[b1+1]) + (red[b2+1] + red[b3+1]);
        const float s2 = (red[b0+2] + red[b1+2]) + (red[b2+2] + red[b3+2]);
        const float s3 = (red[b0+3] + red[b1+3]) + (red[b2+3] + red[b3+3]);
        const float s4 = (red[b0+4] + red[b1+4]) + (red[b2+4] + red[b3+4]);

        float* o = out + (((size_t)n * NS) * WIDTH + (size_t)t) * NANG + (size_t)a;
        float cum = s0;
        o[0]                          = cum * (1.0f / 2.0f);
        cum += s1;
        o[(size_t)1 * WIDTH * NANG]   = cum * (1.0f / 64.0f);
        cum += s2;
        o[(size_t)2 * WIDTH * NANG]   = cum * (1.0f / 128.0f);
        cum += s3;
        o[(size_t)3 * WIDTH * NANG]   = cum * (1.0f / 192.0f);
        cum += s4;
        o[(size_t)4 * WIDTH * NANG]   = cum * (1.0f / 256.0f);
    }
}

extern "C" void kernel_launch(void* const* d_in, const int* in_sizes, int n_in,
                              void* d_out, int out_size, void* d_ws, size_t ws_size,
                              hipStream_t stream) {
    const float* x = (const float*)d_in[0];
    float* out = (float*)d_out;
    radon_kernel<<<NBATCH * NANG, 1024, 0, stream>>>(x, out);
}

// Round 15
// 49.865 us; speedup vs baseline: 1.8384x; 1.8384x over previous
//
#include <hip/hip_runtime.h>

// Partial Radon transform:
//  x: (4, 1, 256, 256) f32 -> out: (4, 5, 256, 180) f32
//
// Round 15 = R12 restored verbatim (best measured: 49.8 us timed).
// Session findings baked in:
//  - single-pass, whole image in LDS as f16 pair-cells (CSTR=131 dwords/row,
//    136 KB -> 1 block/CU, 16 waves); two-pass occupancy schemes lose ~2x
//    (R13/R14: re-stage + window + predicate overhead > TLP gain).
//  - XCD-aware inverse swizzle (720 = 8 x 90): WRITE_SIZE 29 -> 3.8 MB.
//  - angle-chosen layout (transp when |c|>|s|) keeps staging coalesced.
//  - alignbit pair-select + fract + packed-f16 slow-axis lerp: ~22 VALU/sample.
//  - quarter = contiguous 64-h range (stride-4 phase splits with
//    wave-varying windows were the R6/R7 correctness bug; R9's strided
//    unroll serialized DS chains).

constexpr int WIDTH  = 256;
constexpr int NANG   = 180;
constexpr int NBATCH = 4;
constexpr int NS     = 5;
constexpr int CSTR   = 131;   // dword cells per slow-row; 131%32=3
constexpr int ROWS   = 260;   // padded slow: pad 0,1 | orig 2..257 | pad 258,259

typedef _Float16 h2 __attribute__((ext_vector_type(2)));

#if __has_builtin(__builtin_amdgcn_fractf)
#define FRACT(x) __builtin_amdgcn_fractf(x)
#else
#define FRACT(x) ((x) - floorf(x))
#endif

__device__ inline unsigned pack2_f16(float a, float b) {
    _Float16 ha = (_Float16)a, hb = (_Float16)b;
    unsigned short ua = __builtin_bit_cast(unsigned short, ha);
    unsigned short ub = __builtin_bit_cast(unsigned short, hb);
    return (unsigned)ua | ((unsigned)ub << 16);
}

__global__ __launch_bounds__(1024) void radon_kernel(const float* __restrict__ x,
                                                     float* __restrict__ out) {
    __shared__ unsigned cells[ROWS * CSTR];   // 136,240 B static

    // XCD-aware swizzle (720 = 8 XCDs x 90): same-XCD blocks get contiguous
    // (n,a) so stride-720B output stores merge into full lines in its L2.
    const int bid = blockIdx.x;
    const int lin = (bid & 7) * 90 + (bid >> 3);   // bijective on [0,720)
    const int n = lin / NANG;
    const int a = lin - n * NANG;
    const int t = threadIdx.x;
    const int w = t & 255;
    const int quarter = t >> 8;          // contiguous 64-h range per quarter

    const float* __restrict__ img = x + (size_t)n * WIDTH * WIDTH;

    const float theta = (float)a * 0.017453292519943295f;
    float s, c;
    sincosf(theta, &s, &c);
    const bool transp = (c * c > s * s);

    // ---- Zero-fill pad cells + stage interior: DISJOINT sets, one barrier ----
    for (int i = t; i < 2 * CSTR; i += 1024) {       // rows 0,1 and 258,259
        cells[i] = 0u;
        cells[258 * CSTR + i] = 0u;
    }
    if (t < ROWS) {                                  // cols j=0,129,130, all rows
        const int b = t * CSTR;
        cells[b] = 0u; cells[b + 129] = 0u; cells[b + 130] = 0u;
    }

    if (!transp) {
        // slow=y, fast=x. float4 = 4 px = 2 adjacent cells. Coalesced 16B reads.
        #pragma unroll
        for (int i = 0; i < 16; ++i) {
            const int d = t + 1024 * i;              // float4 index in [0,16384)
            const float4 v = ((const float4*)img)[d];
            const int y  = d >> 6;                   // row
            const int j0 = ((d & 63) << 1) + 1;      // first cell (pad +1)
            const int base = (y + 2) * CSTR + j0;
            cells[base]     = pack2_f16(v.x, v.y);
            cells[base + 1] = pack2_f16(v.z, v.w);
        }
    } else {
        // slow=x, fast=y: lane<->x (coalesced rows); cell c = orig y (2c-2,2c-1)
        for (int yp = quarter; yp < 128; yp += 4) {
            const float v0 = img[(2 * yp) * WIDTH + w];
            const float v1 = img[(2 * yp + 1) * WIDTH + w];
            cells[(w + 2) * CSTR + yp + 1] = pack2_f16(v0, v1);
        }
    }
    __syncthreads();

    // ---- Per-(a,w) line walk ----
    const float bw  = ((float)w + 0.5f) * (2.0f / WIDTH) - 1.0f;
    const float bh0 = 0.5f * (2.0f / WIDTH) - 1.0f;
    const float gx0 = c * bw + s * bh0;
    const float gy0 = -s * bw + c * bh0;
    const float ix0 = ((gx0 + 1.0f) * (float)WIDTH - 1.0f) * 0.5f;
    const float iy0 = ((gy0 + 1.0f) * (float)WIDTH - 1.0f) * 0.5f;

    const float fast0 = (transp ? iy0 : ix0) + 2.0f;
    const float slow0 = (transp ? ix0 : iy0) + 2.0f;
    const float dfast = transp ? c : s;
    const float dslow = transp ? s : c;

    float r0 = 0.f, r1 = 0.f, r2 = 0.f, r3 = 0.f, r4 = 0.f;

    auto sample = [&](int h) -> float {
        const float hf = (float)h;
        float fa = fmaf(hf, dfast, fast0);
        float sl = fmaf(hf, dslow, slow0);
        fa = __builtin_amdgcn_fmed3f(fa, 1.0f, 258.0f);
        sl = __builtin_amdgcn_fmed3f(sl, 1.0f, 258.0f);
        const int fi = (int)fa, si = (int)sl;   // trunc == floor (coords >= 1)
        const float wf = FRACT(fa);
        const float ws = FRACT(sl);
        const int j = fi >> 1;
        const int sh = (fi & 1) << 4;
        const unsigned* rowA = &cells[__mul24(si, CSTR) + j];
        const unsigned loA = rowA[0],    hiA = rowA[1];
        const unsigned loB = rowA[CSTR], hiB = rowA[CSTR + 1];
        const unsigned pa = __builtin_amdgcn_alignbit(hiA, loA, sh); // {v00,v01}
        const unsigned pb = __builtin_amdgcn_alignbit(hiB, loB, sh); // {v10,v11}
        const h2 va = __builtin_bit_cast(h2, pa);
        const h2 vb = __builtin_bit_cast(h2, pb);
        const _Float16 wsh = (_Float16)ws;
        const h2 ws2 = {wsh, wsh};
        const h2 col = (vb - va) * ws2 + va;    // packed lerp along slow axis
        const float c0 = (float)col.x;
        const float c1 = (float)col.y;
        return fmaf(wf, c1 - c0, c0);           // f32 lerp along fast axis
    };

    // Ring bands: r4:[0,32)u[224,256)  r3:[32,64)u[192,224)
    //             r2:[64,96)u[160,192) r1:[96,127)u[129,160) r0:{127,128}
    // Uniform 32-trip loops, unroll 16; r0 via per-copy select.
    if (quarter == 0) {
        #pragma unroll 16
        for (int k = 0; k < 32; ++k) r4 += sample(k);
        #pragma unroll 16
        for (int k = 0; k < 32; ++k) r3 += sample(32 + k);
    } else if (quarter == 1) {
        #pragma unroll 16
        for (int k = 0; k < 32; ++k) r2 += sample(64 + k);
        #pragma unroll 16
        for (int k = 0; k < 32; ++k) {
            const float v = sample(96 + k);
            if (k == 31) r0 += v; else r1 += v;   // h==127
        }
    } else if (quarter == 2) {
        #pragma unroll 16
        for (int k = 0; k < 32; ++k) {
            const float v = sample(128 + k);
            if (k == 0) r0 += v; else r1 += v;    // h==128
        }
        #pragma unroll 16
        for (int k = 0; k < 32; ++k) r2 += sample(160 + k);
    } else {
        #pragma unroll 16
        for (int k = 0; k < 32; ++k) r3 += sample(192 + k);
        #pragma unroll 16
        for (int k = 0; k < 32; ++k) r4 += sample(224 + k);
    }

    // ---- Cross-quarter reduction via LDS reuse ----
    __syncthreads();                       // sampling done; image dead
    float* red = (float*)cells;            // 1024*5 floats = 20,480 B
    const int base = t * NS;
    red[base + 0] = r0;
    red[base + 1] = r1;
    red[base + 2] = r2;
    red[base + 3] = r3;
    red[base + 4] = r4;
    __syncthreads();

    if (t < 256) {
        const int b0 = t * NS, b1 = b0 + 256 * NS, b2 = b0 + 512 * NS, b3 = b0 + 768 * NS;
        const float s0 = (red[b0+0] + red[b1+0]) + (red[b2+0] + red[b3+0]);
        const float s1 = (red[b0+1] + red[b1+1]) + (red[b2+1] + red[b3+1]);
        const float s2 = (red[b0+2] + red[b1+2]) + (red[b2+2] + red[b3+2]);
        const float s3 = (red[b0+3] + red[b1+3]) + (red[b2+3] + red[b3+3]);
        const float s4 = (red[b0+4] + red[b1+4]) + (red[b2+4] + red[b3+4]);

        float* o = out + (((size_t)n * NS) * WIDTH + (size_t)t) * NANG + (size_t)a;
        float cum = s0;
        o[0]                          = cum * (1.0f / 2.0f);
        cum += s1;
        o[(size_t)1 * WIDTH * NANG]   = cum * (1.0f / 64.0f);
        cum += s2;
        o[(size_t)2 * WIDTH * NANG]   = cum * (1.0f / 128.0f);
        cum += s3;
        o[(size_t)3 * WIDTH * NANG]   = cum * (1.0f / 192.0f);
        cum += s4;
        o[(size_t)4 * WIDTH * NANG]   = cum * (1.0f / 256.0f);
    }
}

extern "C" void kernel_launch(void* const* d_in, const int* in_sizes, int n_in,
                              void* d_out, int out_size, void* d_ws, size_t ws_size,
                              hipStream_t stream) {
    const float* x = (const float*)d_in[0];
    float* out = (float*)d_out;
    radon_kernel<<<NBATCH * NANG, 1024, 0, stream>>>(x, out);
}